// Round 8
// baseline (186.722 us; speedup 1.0000x reference)
//
#include <hip/hip_runtime.h>
#include <math.h>

#define Tc 1024
#define Dc 256
#define Hc 8
#define Cc 16
#define LUTN 256

typedef __attribute__((ext_vector_type(8))) short short8;
typedef __attribute__((ext_vector_type(4))) float f32x4;

__device__ __forceinline__ unsigned bf16u(float x) {   // RNE
    unsigned u = __float_as_uint(x);
    return (u + 0x7FFFu + ((u >> 16) & 1u)) >> 16;
}
__device__ __forceinline__ unsigned pk2(float lo, float hi) {
    return bf16u(lo) | (bf16u(hi) << 16);
}
__device__ __forceinline__ unsigned pk2t(float lo, float hi) {  // truncating, 1 inst
    return __builtin_amdgcn_perm(__float_as_uint(hi), __float_as_uint(lo), 0x07060302u);
}
__device__ __forceinline__ float upk(unsigned v) { return __uint_as_float(v << 16); }
__device__ __forceinline__ float upkh(unsigned v) { return __uint_as_float(v & 0xffff0000u); }

__device__ __forceinline__ short8 packW8(const float* __restrict__ p) {
    float4 b0 = *(const float4*)(p);
    float4 b1 = *(const float4*)(p + 4);
    union { short8 s; unsigned wds[4]; } B;
    B.wds[0] = pk2(b0.x, b0.y); B.wds[1] = pk2(b0.z, b0.w);
    B.wds[2] = pk2(b1.x, b1.y); B.wds[3] = pk2(b1.z, b1.w);
    return B.s;
}

// ---------------- K1: QKV direct-MFMA GEMM (no LDS in loop, fp32 weights) ---
// grid (256, 3), block 256 = 4 waves. Wave: C tile 16 rows x 64 cols.
// Both A (x) and B (W) read fp32, RNE-packed bf16 in-register (R4-verified).
__global__ __launch_bounds__(256) void qkv_direct(
    const float* __restrict__ x,
    const float* __restrict__ Wq, const float* __restrict__ Wk,
    const float* __restrict__ Wv,
    ushort* __restrict__ Qb, ushort* __restrict__ Kb, ushort* __restrict__ Vt)
{
    const int tid = threadIdx.x;
    const int w = tid >> 6;
    const int l = tid & 63;
    const int u = l & 15, g = l >> 4;
    const int rbase = blockIdx.x * 16;
    const int cb = (blockIdx.y * 4 + w) * 64;     // 0..704
    const int mat = cb >> 8;                      // 0=Q 1=K 2=V
    const int fcb = cb & 255;
    const float* Wmat = (mat == 0) ? Wq : (mat == 1) ? Wk : Wv;

    f32x4 acc[4];
#pragma unroll
    for (int nt = 0; nt < 4; ++nt) acc[nt] = (f32x4){0.f, 0.f, 0.f, 0.f};

    const float* arow = x + (size_t)(rbase + u) * 256 + g * 8;
#pragma unroll 2
    for (int k0 = 0; k0 < 256; k0 += 32) {
        short8 af = packW8(arow + k0);
#pragma unroll
        for (int nt = 0; nt < 4; ++nt) {
            short8 bfr = packW8(Wmat + (size_t)(fcb + nt * 16 + u) * 256 + k0 + g * 8);
            acc[nt] = __builtin_amdgcn_mfma_f32_16x16x32_bf16(af, bfr, acc[nt], 0, 0, 0);
        }
    }

    if (mat < 2) {
        ushort* Out = (mat == 0) ? Qb : Kb;
#pragma unroll
        for (int hp = 0; hp < 2; ++hp) {          // two heads per wave tile
            const int head = (fcb >> 5) + hp;
#pragma unroll
            for (int reg = 0; reg < 4; ++reg) {
                float ss = acc[2 * hp][reg] * acc[2 * hp][reg]
                         + acc[2 * hp + 1][reg] * acc[2 * hp + 1][reg];
                ss += __shfl_xor(ss, 1, 64);
                ss += __shfl_xor(ss, 2, 64);
                ss += __shfl_xor(ss, 4, 64);
                ss += __shfl_xor(ss, 8, 64);
                float scn = 1.f / fmaxf(sqrtf(ss), 1e-12f);
                const int t = rbase + 4 * g + reg;
                const int bb = t >> 10, tt = t & 1023;
                const size_t base = ((size_t)(bb * 8 + head) * Tc + tt) * 32;
                Out[base + u]      = (ushort)bf16u(acc[2 * hp][reg] * scn);
                Out[base + 16 + u] = (ushort)bf16u(acc[2 * hp + 1][reg] * scn);
            }
        }
    } else {
#pragma unroll
        for (int nt = 0; nt < 4; ++nt) {
            const int head = (fcb >> 5) + (nt >> 1);
            const int vt = nt & 1;
#pragma unroll
            for (int reg = 0; reg < 4; ++reg) {
                const int s = rbase + 4 * g + reg;
                const int bb = s >> 10, ss = s & 1023;
                const int bh = bb * 8 + head;
                Vt[(((size_t)bh * 32 + (ss >> 5)) * 2 + vt) * 512 + u * 32 + (ss & 31)] =
                    (ushort)bf16u(acc[nt][reg]);
            }
        }
    }
}

// ---------------- K2: fused flash attention, all 8 heads per block ----------
// grid 256 = (t-tile, b), block 1024 = 16 waves: wave w -> head pair (w>>2),
// s-quarter (w&3)*256. Phase A: block stages rel+mask (16 rows x 1024) ONCE
// into XOR-swizzled LDS as bf16 (masked -> -1.0); 8-head PWL LUT in-block.
// Phase B: swapped-QK LDS-free-P loop (verified): S = mfma(K,Q) puts
// S[t=u][s=8g+2j(+1)] lane-local -> P packs straight into the PV A-fragment.
// bid mapping: b = (bid&7)>>1 so each XCD pair owns one b (K+V 1 MB L2-hot).
__global__ __launch_bounds__(1024) void attn_fused(
    const ushort* __restrict__ Qb, const ushort* __restrict__ Kb,
    const ushort* __restrict__ Vt,
    const float* __restrict__ rel, const int* __restrict__ msk,
    const float* __restrict__ pw1, const float* __restrict__ pb1,
    const float* __restrict__ pw2, const float* __restrict__ pb2,
    ushort* __restrict__ Yb)
{
    const int tid = threadIdx.x;
    const int w = tid >> 6;
    const int l = tid & 63;
    const int u = l & 15;
    const int g = l >> 4;
    const int bid = blockIdx.x;
    const int c   = bid & 7;
    const int b   = c >> 1;                        // XCD-pair-local b
    const int tt  = (bid >> 3) * 2 + (c & 1);      // 0..63
    const int t0  = tt * 16;

    __shared__ __align__(16) ushort dm_s[16 * 1024];    // 32 KB, XOR-swizzled
    __shared__ __align__(16) ushort lut_s[256 * 16];    // 8 KB [bin][head]{a,b}
    __shared__ __align__(16) ushort comb[16 * 16 * 64]; // 32 KB bf16 partials
    __shared__ float rs_s[16 * 2 * 16];                 // 2 KB [w][hi][t]

    // ---- build the 8-head PWL LUT (each (bin, head-pair) by one thread) ----
    {
        const int bin = tid & 255;
        const int hb  = (tid >> 8) * 2;
#pragma unroll
        for (int hp = 0; hp < 2; ++hp) {
            const int h = hb + hp;
            const float d0 = bin * (1.f / LUTN), d1 = (bin + 1) * (1.f / LUTN);
            float y0 = pb2[h], y1 = pb2[h];
#pragma unroll
            for (int cc = 0; cc < Cc; ++cc) {
                float w1 = pw1[h * Cc + cc], b1 = pb1[h * Cc + cc], w2 = pw2[h * Cc + cc];
                float h0 = fmaf(w1, d0, b1), h1 = fmaf(w1, d1, b1);
                y0 = fmaf(w2, h0 >= 0.f ? h0 : 0.01f * h0, y0);
                y1 = fmaf(w2, h1 >= 0.f ? h1 : 0.01f * h1, y1);
            }
            float a = (y1 - y0) * (float)LUTN;
            float bq = y0 - a * d0;
            lut_s[bin * 16 + h * 2]     = (ushort)bf16u(a);
            lut_s[bin * 16 + h * 2 + 1] = (ushort)bf16u(bq);
        }
    }

    // ---- stage rel+mask -> swizzled bf16 dm_s (read once chip-wide) --------
    {
        const int row = tid >> 6;            // 0..15
        const int lc  = tid & 63;
        const float* rrow = rel + ((size_t)b * Tc + t0 + row) * Tc;
        const int*   mrow = msk + ((size_t)b * Tc + t0 + row) * Tc;
        const int swz = (row & 7) << 4;
#pragma unroll
        for (int i = 0; i < 2; ++i) {
            const int s0 = lc * 8 + i * 512;
            float4 d0v = *(const float4*)(rrow + s0);
            float4 d1v = *(const float4*)(rrow + s0 + 4);
            int4   m0v = *(const int4*)(mrow + s0);
            int4   m1v = *(const int4*)(mrow + s0 + 4);
            uint4 p;
            p.x = (m0v.x ? 0xBF80u : bf16u(d0v.x)) | ((m0v.y ? 0xBF80u : bf16u(d0v.y)) << 16);
            p.y = (m0v.z ? 0xBF80u : bf16u(d0v.z)) | ((m0v.w ? 0xBF80u : bf16u(d0v.w)) << 16);
            p.z = (m1v.x ? 0xBF80u : bf16u(d1v.x)) | ((m1v.y ? 0xBF80u : bf16u(d1v.y)) << 16);
            p.w = (m1v.z ? 0xBF80u : bf16u(d1v.z)) | ((m1v.w ? 0xBF80u : bf16u(d1v.w)) << 16);
            *(uint4*)((char*)dm_s + ((row * 2048 + s0 * 2) ^ swz)) = p;
        }
    }

    const int hgp = w >> 2;                     // head pair 0..3
    const int bh0 = b * 8 + hgp * 2;
    short8 qf[2];
#pragma unroll
    for (int hi = 0; hi < 2; ++hi)
        qf[hi] = *(const short8*)(Qb + (((size_t)(bh0 + hi) * Tc + t0 + u) * 32 + g * 8));

    const short8 ones = (short8){0x3F80, 0x3F80, 0x3F80, 0x3F80,
                                 0x3F80, 0x3F80, 0x3F80, 0x3F80};

    f32x4 oacc[2][2];
    f32x4 rsacc[2];
#pragma unroll
    for (int hi = 0; hi < 2; ++hi) {
        oacc[hi][0] = (f32x4){0.f, 0.f, 0.f, 0.f};
        oacc[hi][1] = (f32x4){0.f, 0.f, 0.f, 0.f};
        rsacc[hi]   = (f32x4){0.f, 0.f, 0.f, 0.f};
    }

    __syncthreads();   // lut + dm staged

    const int s_begin = (w & 3) * 256;
    const int dswz = (u & 7) << 4;

    // software-rotated K (one iteration ahead; no barriers in the loop)
    short8 kc[2][2];
#pragma unroll
    for (int hi = 0; hi < 2; ++hi) {
        const size_t kb = ((size_t)(bh0 + hi) * Tc + s_begin + 2 * u) * 32 + g * 8;
        kc[hi][0] = *(const short8*)(Kb + kb);
        kc[hi][1] = *(const short8*)(Kb + kb + 32);
    }

    for (int sc = s_begin; sc < s_begin + 256; sc += 32) {
        const int nx = (sc + 32 < s_begin + 256) ? sc + 32 : s_begin;  // clamped prefetch
        short8 kn[2][2];
#pragma unroll
        for (int hi = 0; hi < 2; ++hi) {
            const size_t kb = ((size_t)(bh0 + hi) * Tc + nx + 2 * u) * 32 + g * 8;
            kn[hi][0] = *(const short8*)(Kb + kb);
            kn[hi][1] = *(const short8*)(Kb + kb + 32);
        }

        // d for s = sc + 8g + {2j, 2j+1}, row t = u (LDS, swizzled)
        uint4 dmv = *(const uint4*)((const char*)dm_s + ((u * 2048 + (sc + 8 * g) * 2) ^ dswz));
        const unsigned dw[4] = {dmv.x, dmv.y, dmv.z, dmv.w};
        float dA[4], dB[4];
#pragma unroll
        for (int j = 0; j < 4; ++j) {
            dA[j] = upk(dw[j]);
            dB[j] = upkh(dw[j]);
        }
        float biasA[4][2], biasB[4][2];
#pragma unroll
        for (int j = 0; j < 4; ++j) {
            int iA = (int)(dA[j] * (float)LUTN);
            int iB = (int)(dB[j] * (float)LUTN);
            iA = iA < 0 ? 0 : (iA > LUTN - 1 ? LUTN - 1 : iA);
            iB = iB < 0 ? 0 : (iB > LUTN - 1 ? LUTN - 1 : iB);
            uint2 wA = *(const uint2*)(lut_s + iA * 16 + hgp * 4);
            uint2 wB = *(const uint2*)(lut_s + iB * 16 + hgp * 4);
            biasA[j][0] = fmaf(upk(wA.x), dA[j], upkh(wA.x));
            biasA[j][1] = fmaf(upk(wA.y), dA[j], upkh(wA.y));
            biasB[j][0] = fmaf(upk(wB.x), dB[j], upkh(wB.x));
            biasB[j][1] = fmaf(upk(wB.y), dB[j], upkh(wB.y));
        }
#pragma unroll
        for (int hi = 0; hi < 2; ++hi) {
            const f32x4 z4 = (f32x4){0.f, 0.f, 0.f, 0.f};
            // swapped operands: rows of C = K rows (s), cols = Q rows (t=u)
            f32x4 sA = __builtin_amdgcn_mfma_f32_16x16x32_bf16(kc[hi][0], qf[hi], z4, 0, 0, 0);
            f32x4 sB = __builtin_amdgcn_mfma_f32_16x16x32_bf16(kc[hi][1], qf[hi], z4, 0, 0, 0);
            union { short8 s; unsigned w4[4]; } P;
#pragma unroll
            for (int j = 0; j < 4; ++j) {
                float zA = (dA[j] < 0.f) ? 0.f : __expf(sA[j] - biasA[j][hi]);
                float zB = (dB[j] < 0.f) ? 0.f : __expf(sB[j] - biasB[j][hi]);
                P.w4[j] = pk2t(zA, zB);
            }
            const ushort* vb = Vt + ((size_t)(bh0 + hi) * 32 + (sc >> 5)) * 1024;
            short8 vf0 = *(const short8*)(vb + u * 32 + g * 8);
            short8 vf1 = *(const short8*)(vb + 512 + u * 32 + g * 8);
            oacc[hi][0] = __builtin_amdgcn_mfma_f32_16x16x32_bf16(P.s, vf0, oacc[hi][0], 0, 0, 0);
            oacc[hi][1] = __builtin_amdgcn_mfma_f32_16x16x32_bf16(P.s, vf1, oacc[hi][1], 0, 0, 0);
            rsacc[hi]   = __builtin_amdgcn_mfma_f32_16x16x32_bf16(P.s, ones, rsacc[hi], 0, 0, 0);
        }
#pragma unroll
        for (int hi = 0; hi < 2; ++hi) {
            kc[hi][0] = kn[hi][0];
            kc[hi][1] = kn[hi][1];
        }
    }

    // rowsums already reduced by the ones-MFMA (all u columns equal)
#pragma unroll
    for (int hi = 0; hi < 2; ++hi)
        if (u == 0) {
#pragma unroll
            for (int reg = 0; reg < 4; ++reg)
                rs_s[(w * 2 + hi) * 16 + 4 * g + reg] = rsacc[hi][reg];
        }
#pragma unroll
    for (int hi = 0; hi < 2; ++hi)
#pragma unroll
        for (int vt = 0; vt < 2; ++vt)
#pragma unroll
            for (int reg = 0; reg < 4; ++reg)
                comb[w * 1024 + (4 * g + reg) * 64 + hi * 32 + vt * 16 + u] =
                    (ushort)(__float_as_uint(oacc[hi][vt][reg]) >> 16);
    __syncthreads();

    // combine the 4 s-quarter waves per head pair; write full 256-col Y rows.
    if (tid < 512) {
        const int tl = tid >> 5;
        const int f0 = (tid & 31) * 8;
        const int hgp2 = f0 >> 6;
        const int hi = (f0 >> 5) & 1;
        const int w0 = hgp2 * 4;
        float rstot = rs_s[((w0 + 0) * 2 + hi) * 16 + tl]
                    + rs_s[((w0 + 1) * 2 + hi) * 16 + tl]
                    + rs_s[((w0 + 2) * 2 + hi) * 16 + tl]
                    + rs_s[((w0 + 3) * 2 + hi) * 16 + tl];
        float inv = 1.f / (rstot + 1e-5f);
        float o[8];
#pragma unroll
        for (int k = 0; k < 8; ++k) o[k] = 0.f;
#pragma unroll
        for (int q = 0; q < 4; ++q) {
            uint4 pv = *(const uint4*)&comb[(w0 + q) * 1024 + tl * 64 + (f0 & 63)];
            o[0] += upk(pv.x); o[1] += upkh(pv.x);
            o[2] += upk(pv.y); o[3] += upkh(pv.y);
            o[4] += upk(pv.z); o[5] += upkh(pv.z);
            o[6] += upk(pv.w); o[7] += upkh(pv.w);
        }
        uint4 pwv;
        pwv.x = pk2(o[0] * inv, o[1] * inv); pwv.y = pk2(o[2] * inv, o[3] * inv);
        pwv.z = pk2(o[4] * inv, o[5] * inv); pwv.w = pk2(o[6] * inv, o[7] * inv);
        *(uint4*)(Yb + ((size_t)b * Tc + t0 + tl) * Dc + f0) = pwv;
    }
}

// ---------------- K3: fused Wo-GEMM+LN1 -> FFN-GEMM+LN2 (fp32 weights) ------
// grid 256, block 512 = 8 waves; block owns 16 rows x all 256 cols.
// ZZ tile lives in XOR-swizzled LDS between the two GEMMs; fp32 residual in regs.
__global__ __launch_bounds__(512) void out_fused(
    const ushort* __restrict__ Yb, const float* __restrict__ Wo,
    const float* __restrict__ bo, const float* __restrict__ x,
    const float* __restrict__ g1, const float* __restrict__ be1,
    const float* __restrict__ Wf, const float* __restrict__ bfb,
    const float* __restrict__ g2, const float* __restrict__ be2,
    float* __restrict__ out)
{
    const int tid = threadIdx.x;
    const int w = tid >> 6;                 // wave 0..7: cols [w*32, w*32+32)
    const int l = tid & 63;
    const int u = l & 15, g = l >> 4;
    const int rbase = blockIdx.x * 16;

    __shared__ float red1[128], red2[128];
    __shared__ __align__(16) ushort ZZs[16 * 256];   // 8 KB, XOR-swizzled

    // ---- phase 1: Y @ Wo^T + bo + x, LN1 -> ZZ ----
    f32x4 acc[2];
    acc[0] = (f32x4){0.f, 0.f, 0.f, 0.f};
    acc[1] = (f32x4){0.f, 0.f, 0.f, 0.f};
    const ushort* arow = Yb + (size_t)(rbase + u) * 256 + g * 8;
#pragma unroll 2
    for (int k0 = 0; k0 < 256; k0 += 32) {
        short8 af = *(const short8*)(arow + k0);
#pragma unroll
        for (int nt = 0; nt < 2; ++nt) {
            short8 bfr = packW8(Wo + (size_t)(w * 32 + nt * 16 + u) * 256 + k0 + g * 8);
            acc[nt] = __builtin_amdgcn_mfma_f32_16x16x32_bf16(af, bfr, acc[nt], 0, 0, 0);
        }
    }

    float bv[2];
#pragma unroll
    for (int nt = 0; nt < 2; ++nt) bv[nt] = bo[w * 32 + nt * 16 + u];

    float sv[4][2];
#pragma unroll
    for (int reg = 0; reg < 4; ++reg) {
        const int row = rbase + 4 * g + reg;
        float s1 = 0.f, s2 = 0.f;
#pragma unroll
        for (int nt = 0; nt < 2; ++nt) {
            const int col = w * 32 + nt * 16 + u;
            float s = acc[nt][reg] + bv[nt] + x[(size_t)row * 256 + col];
            sv[reg][nt] = s;
            s1 += s;
            s2 = fmaf(s, s, s2);
        }
        s1 += __shfl_xor(s1, 1, 64); s2 += __shfl_xor(s2, 1, 64);
        s1 += __shfl_xor(s1, 2, 64); s2 += __shfl_xor(s2, 2, 64);
        s1 += __shfl_xor(s1, 4, 64); s2 += __shfl_xor(s2, 4, 64);
        s1 += __shfl_xor(s1, 8, 64); s2 += __shfl_xor(s2, 8, 64);
        if (u == 0) { red1[w * 16 + 4 * g + reg] = s1; red2[w * 16 + 4 * g + reg] = s2; }
    }
    __syncthreads();

    float zzv[4][2];   // fp32 residual for phase 2
#pragma unroll
    for (int reg = 0; reg < 4; ++reg) {
        const int rl = 4 * g + reg;
        float S1 = 0.f, S2 = 0.f;
#pragma unroll
        for (int ww = 0; ww < 8; ++ww) { S1 += red1[ww * 16 + rl]; S2 += red2[ww * 16 + rl]; }
        float mu = S1 * (1.f / 256.f);
        float var = S2 * (1.f / 256.f) - mu * mu;
        float rsig = rsqrtf(var + 1e-5f);
#pragma unroll
        for (int nt = 0; nt < 2; ++nt) {
            const int col = w * 32 + nt * 16 + u;
            float zz = (sv[reg][nt] - mu) * rsig * g1[col] + be1[col];
            zzv[reg][nt] = zz;
            const int boff = (rl * 512 + col * 2) ^ ((rl & 7) << 4);
            *(ushort*)((char*)ZZs + boff) = (ushort)bf16u(zz);
        }
    }
    __syncthreads();   // ZZ staged

    // ---- phase 2: ZZ @ Wf^T + bf, lrelu, + ZZ, LN2 -> out ----
    f32x4 acc2[2];
    acc2[0] = (f32x4){0.f, 0.f, 0.f, 0.f};
    acc2[1] = (f32x4){0.f, 0.f, 0.f, 0.f};
#pragma unroll 2
    for (int k0 = 0; k0 < 256; k0 += 32) {
        const int aoff = (u * 512 + (k0 + g * 8) * 2) ^ ((u & 7) << 4);
        short8 af = *(const short8*)((const char*)ZZs + aoff);
#pragma unroll
        for (int nt = 0; nt < 2; ++nt) {
            short8 bfr = packW8(Wf + (size_t)(w * 32 + nt * 16 + u) * 256 + k0 + g * 8);
            acc2[nt] = __builtin_amdgcn_mfma_f32_16x16x32_bf16(af, bfr, acc2[nt], 0, 0, 0);
        }
    }

    float bv2[2];
#pragma unroll
    for (int nt = 0; nt < 2; ++nt) bv2[nt] = bfb[w * 32 + nt * 16 + u];

    float sv2[4][2];
#pragma unroll
    for (int reg = 0; reg < 4; ++reg) {
        float s1 = 0.f, s2 = 0.f;
#pragma unroll
        for (int nt = 0; nt < 2; ++nt) {
            float v = acc2[nt][reg] + bv2[nt];
            v = v >= 0.f ? v : 0.01f * v;
            float s = v + zzv[reg][nt];
            sv2[reg][nt] = s;
            s1 += s;
            s2 = fmaf(s, s, s2);
        }
        s1 += __shfl_xor(s1, 1, 64); s2 += __shfl_xor(s2, 1, 64);
        s1 += __shfl_xor(s1, 2, 64); s2 += __shfl_xor(s2, 2, 64);
        s1 += __shfl_xor(s1, 4, 64); s2 += __shfl_xor(s2, 4, 64);
        s1 += __shfl_xor(s1, 8, 64); s2 += __shfl_xor(s2, 8, 64);
        if (u == 0) { red1[w * 16 + 4 * g + reg] = s1; red2[w * 16 + 4 * g + reg] = s2; }
    }
    __syncthreads();

#pragma unroll
    for (int reg = 0; reg < 4; ++reg) {
        const int row = rbase + 4 * g + reg;
        const int rl = 4 * g + reg;
        float S1 = 0.f, S2 = 0.f;
#pragma unroll
        for (int ww = 0; ww < 8; ++ww) { S1 += red1[ww * 16 + rl]; S2 += red2[ww * 16 + rl]; }
        float mu = S1 * (1.f / 256.f);
        float var = S2 * (1.f / 256.f) - mu * mu;
        float rsig = rsqrtf(var + 1e-5f);
#pragma unroll
        for (int nt = 0; nt < 2; ++nt) {
            const int col = w * 32 + nt * 16 + u;
            out[(size_t)row * 256 + col] = (sv2[reg][nt] - mu) * rsig * g2[col] + be2[col];
        }
    }
}

extern "C" void kernel_launch(void* const* d_in, const int* in_sizes, int n_in,
                              void* d_out, int out_size, void* d_ws, size_t ws_size,
                              hipStream_t stream) {
    const float* x    = (const float*)d_in[0];
    const int*   mask = (const int*)d_in[1];
    const float* rel  = (const float*)d_in[2];
    const float* Wq   = (const float*)d_in[3];
    const float* Wk   = (const float*)d_in[4];
    const float* Wv   = (const float*)d_in[5];
    const float* pw1  = (const float*)d_in[6];
    const float* pb1  = (const float*)d_in[7];
    const float* pw2  = (const float*)d_in[8];
    const float* pb2  = (const float*)d_in[9];
    const float* Wo   = (const float*)d_in[10];
    const float* bo   = (const float*)d_in[11];
    const float* Wf   = (const float*)d_in[12];
    const float* bf   = (const float*)d_in[13];
    const float* g1   = (const float*)d_in[14];
    const float* be1  = (const float*)d_in[15];
    const float* g2   = (const float*)d_in[16];
    const float* be2  = (const float*)d_in[17];
    float* out = (float*)d_out;

    char* wsb = (char*)d_ws;
    ushort* Qb = (ushort*)(wsb);                       // 2 MB
    ushort* Kb = (ushort*)(wsb + (size_t)(2 << 20));   // 2 MB
    ushort* Vt = (ushort*)(wsb + (size_t)(4 << 20));   // 2 MB (tile-major)
    ushort* Yb = (ushort*)(wsb + (size_t)(6 << 20));   // 2 MB

    qkv_direct<<<dim3(256, 3), 256, 0, stream>>>(x, Wq, Wk, Wv, Qb, Kb, Vt);
    attn_fused<<<256, 1024, 0, stream>>>(Qb, Kb, Vt, rel, mask,
                                         pw1, pb1, pw2, pb2, Yb);
    out_fused<<<256, 512, 0, stream>>>(Yb, Wo, bo, x, g1, be1,
                                       Wf, bf, g2, be2, out);
}

// Round 9
// 171.147 us; speedup vs baseline: 1.0910x; 1.0910x over previous
//
#include <hip/hip_runtime.h>
#include <math.h>

#define Tc 1024
#define Dc 256
#define Hc 8
#define Cc 16
#define LUTN 256

typedef __attribute__((ext_vector_type(8))) short short8;
typedef __attribute__((ext_vector_type(4))) float f32x4;

__device__ __forceinline__ unsigned bf16u(float x) {   // RNE
    unsigned u = __float_as_uint(x);
    return (u + 0x7FFFu + ((u >> 16) & 1u)) >> 16;
}
__device__ __forceinline__ unsigned pk2(float lo, float hi) {
    return bf16u(lo) | (bf16u(hi) << 16);
}
__device__ __forceinline__ unsigned pk2t(float lo, float hi) {  // truncating, 1 inst
    return __builtin_amdgcn_perm(__float_as_uint(hi), __float_as_uint(lo), 0x07060302u);
}
__device__ __forceinline__ float upk(unsigned v) { return __uint_as_float(v << 16); }
__device__ __forceinline__ float upkh(unsigned v) { return __uint_as_float(v & 0xffff0000u); }

__device__ __forceinline__ short8 packW8(const float* __restrict__ p) {
    float4 b0 = *(const float4*)(p);
    float4 b1 = *(const float4*)(p + 4);
    union { short8 s; unsigned wds[4]; } B;
    B.wds[0] = pk2(b0.x, b0.y); B.wds[1] = pk2(b0.z, b0.w);
    B.wds[2] = pk2(b1.x, b1.y); B.wds[3] = pk2(b1.z, b1.w);
    return B.s;
}

// ---------------- K0: cast the 5 weight matrices to bf16 --------------------
// grid 320, block 256; 4 elems/thread.
__global__ __launch_bounds__(256) void cast_w(
    const float* __restrict__ Wq, const float* __restrict__ Wk,
    const float* __restrict__ Wv, const float* __restrict__ Wo,
    const float* __restrict__ Wf,
    ushort* __restrict__ Wqkvc, ushort* __restrict__ Woc,
    ushort* __restrict__ Wfc)
{
    const int e = blockIdx.x * 1024 + threadIdx.x * 4;
    const float* src; ushort* dst; int off;
    if      (e <  65536) { src = Wq; dst = Wqkvc;          off = e; }
    else if (e < 131072) { src = Wk; dst = Wqkvc + 65536;  off = e - 65536; }
    else if (e < 196608) { src = Wv; dst = Wqkvc + 131072; off = e - 131072; }
    else if (e < 262144) { src = Wo; dst = Woc;            off = e - 196608; }
    else                 { src = Wf; dst = Wfc;            off = e - 262144; }
    float4 v = *(const float4*)(src + off);
    uint2 p; p.x = pk2(v.x, v.y); p.y = pk2(v.z, v.w);
    *(uint2*)(dst + off) = p;
}

// ---------------- K1: QKV direct-MFMA GEMM (no LDS, no barriers) ------------
// grid (256, 3), block 256 = 4 waves. Wave: C tile 16 rows x 64 cols.
// A (x) read fp32 and RNE-packed in-register; B from precast bf16 weights.
__global__ __launch_bounds__(256) void qkv_direct(
    const float* __restrict__ x, const ushort* __restrict__ Wqkv,
    ushort* __restrict__ Qb, ushort* __restrict__ Kb, ushort* __restrict__ Vt)
{
    const int tid = threadIdx.x;
    const int w = tid >> 6;
    const int l = tid & 63;
    const int u = l & 15, g = l >> 4;
    const int rbase = blockIdx.x * 16;
    const int cb = (blockIdx.y * 4 + w) * 64;     // 0..704

    f32x4 acc[4];
#pragma unroll
    for (int nt = 0; nt < 4; ++nt) acc[nt] = (f32x4){0.f, 0.f, 0.f, 0.f};

    const float* arow = x + (size_t)(rbase + u) * 256 + g * 8;
#pragma unroll 2
    for (int k0 = 0; k0 < 256; k0 += 32) {
        short8 af = packW8(arow + k0);
#pragma unroll
        for (int nt = 0; nt < 4; ++nt) {
            short8 bfr = *(const short8*)(Wqkv + (size_t)(cb + nt * 16 + u) * 256 + k0 + g * 8);
            acc[nt] = __builtin_amdgcn_mfma_f32_16x16x32_bf16(af, bfr, acc[nt], 0, 0, 0);
        }
    }

    const int mat = cb >> 8;
    const int fcb = cb & 255;
    if (mat < 2) {
        ushort* Out = (mat == 0) ? Qb : Kb;
#pragma unroll
        for (int hp = 0; hp < 2; ++hp) {          // two heads per wave tile
            const int head = (fcb >> 5) + hp;
#pragma unroll
            for (int reg = 0; reg < 4; ++reg) {
                float ss = acc[2 * hp][reg] * acc[2 * hp][reg]
                         + acc[2 * hp + 1][reg] * acc[2 * hp + 1][reg];
                ss += __shfl_xor(ss, 1, 64);
                ss += __shfl_xor(ss, 2, 64);
                ss += __shfl_xor(ss, 4, 64);
                ss += __shfl_xor(ss, 8, 64);
                float scn = 1.f / fmaxf(sqrtf(ss), 1e-12f);
                const int t = rbase + 4 * g + reg;
                const int bb = t >> 10, tt = t & 1023;
                const size_t base = ((size_t)(bb * 8 + head) * Tc + tt) * 32;
                Out[base + u]      = (ushort)bf16u(acc[2 * hp][reg] * scn);
                Out[base + 16 + u] = (ushort)bf16u(acc[2 * hp + 1][reg] * scn);
            }
        }
    } else {
#pragma unroll
        for (int nt = 0; nt < 4; ++nt) {
            const int head = (fcb >> 5) + (nt >> 1);
            const int vt = nt & 1;
#pragma unroll
            for (int reg = 0; reg < 4; ++reg) {
                const int s = rbase + 4 * g + reg;
                const int bb = s >> 10, ss = s & 1023;
                const int bh = bb * 8 + head;
                Vt[(((size_t)bh * 32 + (ss >> 5)) * 2 + vt) * 512 + u * 32 + (ss & 31)] =
                    (ushort)bf16u(acc[nt][reg]);
            }
        }
    }
}

// ---------------- K2: fused flash attention, all 8 heads per block ----------
// grid 256 = (t-tile, b), block 512 = 8 waves: wave w -> head pair (w>>1),
// s-half (w&1)*512. Phase A: block stages rel+mask (16 rows x 1024) ONCE into
// XOR-swizzled LDS as bf16 (masked -> -1.0). Phase B: swapped-QK LDS-free-P
// inner loop (verified): S = mfma(K,Q) puts S[t=u][s=8g+2j(+1)] lane-local ->
// P packs straight into the PV A-fragment. 8-head PWL LUT built in-block.
// R9 change vs R6: dm_s LDS read software-rotated one iteration ahead.
__global__ __launch_bounds__(512) void attn_fused(
    const ushort* __restrict__ Qb, const ushort* __restrict__ Kb,
    const ushort* __restrict__ Vt,
    const float* __restrict__ rel, const int* __restrict__ msk,
    const float* __restrict__ pw1, const float* __restrict__ pb1,
    const float* __restrict__ pw2, const float* __restrict__ pb2,
    ushort* __restrict__ Yb)
{
    const int tid = threadIdx.x;
    const int w = tid >> 6;
    const int l = tid & 63;
    const int u = l & 15;
    const int g = l >> 4;
    const int bid = blockIdx.x;
    const int b   = (bid >> 1) & 3;
    const int tt  = (bid >> 3) * 2 + (bid & 1);   // 0..63
    const int t0  = tt * 16;

    __shared__ __align__(16) ushort dm_s[16 * 1024];    // 32 KB, XOR-swizzled
    __shared__ __align__(16) ushort lut_s[256 * 16];    // 8 KB [bin][head]{a,b}
    __shared__ __align__(16) ushort comb[8 * 16 * 64];  // 16 KB bf16 partials
    __shared__ float rs_s[8 * 2 * 16];                  // 1 KB [w][hi][t]

    // ---- build the 8-head PWL LUT (each (bin, head-quad) by one thread) ----
    {
        const int bin = tid & 255;
        const int hb  = (tid >> 8) * 4;
        const float d0 = bin * (1.f / LUTN), d1 = (bin + 1) * (1.f / LUTN);
#pragma unroll
        for (int hp = 0; hp < 4; ++hp) {
            const int h = hb + hp;
            float y0 = pb2[h], y1 = pb2[h];
#pragma unroll
            for (int cc = 0; cc < Cc; ++cc) {
                float w1 = pw1[h * Cc + cc], b1 = pb1[h * Cc + cc], w2 = pw2[h * Cc + cc];
                float h0 = fmaf(w1, d0, b1), h1 = fmaf(w1, d1, b1);
                y0 = fmaf(w2, h0 >= 0.f ? h0 : 0.01f * h0, y0);
                y1 = fmaf(w2, h1 >= 0.f ? h1 : 0.01f * h1, y1);
            }
            float a = (y1 - y0) * (float)LUTN;
            float bq = y0 - a * d0;
            lut_s[bin * 16 + h * 2]     = (ushort)bf16u(a);
            lut_s[bin * 16 + h * 2 + 1] = (ushort)bf16u(bq);
        }
    }

    // ---- stage rel+mask -> swizzled bf16 dm_s (read once chip-wide) --------
    {
        const int row = tid >> 5;            // 0..15
        const int lc  = tid & 31;
        const float* rrow = rel + ((size_t)b * Tc + t0 + row) * Tc;
        const int*   mrow = msk + ((size_t)b * Tc + t0 + row) * Tc;
        const int swz = (row & 7) << 4;
#pragma unroll
        for (int i = 0; i < 4; ++i) {
            const int s0 = lc * 8 + i * 256;
            float4 d0v = *(const float4*)(rrow + s0);
            float4 d1v = *(const float4*)(rrow + s0 + 4);
            int4   m0v = *(const int4*)(mrow + s0);
            int4   m1v = *(const int4*)(mrow + s0 + 4);
            uint4 p;
            p.x = (m0v.x ? 0xBF80u : bf16u(d0v.x)) | ((m0v.y ? 0xBF80u : bf16u(d0v.y)) << 16);
            p.y = (m0v.z ? 0xBF80u : bf16u(d0v.z)) | ((m0v.w ? 0xBF80u : bf16u(d0v.w)) << 16);
            p.z = (m1v.x ? 0xBF80u : bf16u(d1v.x)) | ((m1v.y ? 0xBF80u : bf16u(d1v.y)) << 16);
            p.w = (m1v.z ? 0xBF80u : bf16u(d1v.z)) | ((m1v.w ? 0xBF80u : bf16u(d1v.w)) << 16);
            *(uint4*)((char*)dm_s + ((row * 2048 + s0 * 2) ^ swz)) = p;
        }
    }

    const int hgp = w >> 1;                     // head pair 0..3
    const int bh0 = b * 8 + hgp * 2;
    short8 qf[2];
#pragma unroll
    for (int hi = 0; hi < 2; ++hi)
        qf[hi] = *(const short8*)(Qb + (((size_t)(bh0 + hi) * Tc + t0 + u) * 32 + g * 8));

    const short8 ones = (short8){0x3F80, 0x3F80, 0x3F80, 0x3F80,
                                 0x3F80, 0x3F80, 0x3F80, 0x3F80};

    f32x4 oacc[2][2];
    f32x4 rsacc[2];
#pragma unroll
    for (int hi = 0; hi < 2; ++hi) {
        oacc[hi][0] = (f32x4){0.f, 0.f, 0.f, 0.f};
        oacc[hi][1] = (f32x4){0.f, 0.f, 0.f, 0.f};
        rsacc[hi]   = (f32x4){0.f, 0.f, 0.f, 0.f};
    }

    __syncthreads();   // lut + dm staged

    const int s_begin = (w & 1) * 512;
    const int dswz = (u & 7) << 4;

    // software-rotated K + dm (one iteration ahead; no barriers in the loop)
    short8 kc[2][2];
#pragma unroll
    for (int hi = 0; hi < 2; ++hi) {
        const size_t kb = ((size_t)(bh0 + hi) * Tc + s_begin + 2 * u) * 32 + g * 8;
        kc[hi][0] = *(const short8*)(Kb + kb);
        kc[hi][1] = *(const short8*)(Kb + kb + 32);
    }
    uint4 dmv = *(const uint4*)((const char*)dm_s + ((u * 2048 + (s_begin + 8 * g) * 2) ^ dswz));

    for (int sc = s_begin; sc < s_begin + 512; sc += 32) {
        const int nx = (sc + 32 < s_begin + 512) ? sc + 32 : s_begin;  // clamped prefetch
        uint4 dmn = *(const uint4*)((const char*)dm_s + ((u * 2048 + (nx + 8 * g) * 2) ^ dswz));
        short8 kn[2][2];
#pragma unroll
        for (int hi = 0; hi < 2; ++hi) {
            const size_t kb = ((size_t)(bh0 + hi) * Tc + nx + 2 * u) * 32 + g * 8;
            kn[hi][0] = *(const short8*)(Kb + kb);
            kn[hi][1] = *(const short8*)(Kb + kb + 32);
        }

        // d for s = sc + 8g + {2j, 2j+1}, row t = u (LDS, swizzled, prefetched)
        const unsigned dw[4] = {dmv.x, dmv.y, dmv.z, dmv.w};
        float dA[4], dB[4];
#pragma unroll
        for (int j = 0; j < 4; ++j) {
            dA[j] = upk(dw[j]);
            dB[j] = upkh(dw[j]);
        }
        float biasA[4][2], biasB[4][2];
#pragma unroll
        for (int j = 0; j < 4; ++j) {
            int iA = (int)(dA[j] * (float)LUTN);
            int iB = (int)(dB[j] * (float)LUTN);
            iA = iA < 0 ? 0 : (iA > LUTN - 1 ? LUTN - 1 : iA);
            iB = iB < 0 ? 0 : (iB > LUTN - 1 ? LUTN - 1 : iB);
            uint2 wA = *(const uint2*)(lut_s + iA * 16 + hgp * 4);
            uint2 wB = *(const uint2*)(lut_s + iB * 16 + hgp * 4);
            biasA[j][0] = fmaf(upk(wA.x), dA[j], upkh(wA.x));
            biasA[j][1] = fmaf(upk(wA.y), dA[j], upkh(wA.y));
            biasB[j][0] = fmaf(upk(wB.x), dB[j], upkh(wB.x));
            biasB[j][1] = fmaf(upk(wB.y), dB[j], upkh(wB.y));
        }
#pragma unroll
        for (int hi = 0; hi < 2; ++hi) {
            const f32x4 z4 = (f32x4){0.f, 0.f, 0.f, 0.f};
            // swapped operands: rows of C = K rows (s), cols = Q rows (t=u)
            f32x4 sA = __builtin_amdgcn_mfma_f32_16x16x32_bf16(kc[hi][0], qf[hi], z4, 0, 0, 0);
            f32x4 sB = __builtin_amdgcn_mfma_f32_16x16x32_bf16(kc[hi][1], qf[hi], z4, 0, 0, 0);
            union { short8 s; unsigned w4[4]; } P;
#pragma unroll
            for (int j = 0; j < 4; ++j) {
                float zA = (dA[j] < 0.f) ? 0.f : __expf(sA[j] - biasA[j][hi]);
                float zB = (dB[j] < 0.f) ? 0.f : __expf(sB[j] - biasB[j][hi]);
                P.w4[j] = pk2t(zA, zB);
            }
            const ushort* vb = Vt + ((size_t)(bh0 + hi) * 32 + (sc >> 5)) * 1024;
            short8 vf0 = *(const short8*)(vb + u * 32 + g * 8);
            short8 vf1 = *(const short8*)(vb + 512 + u * 32 + g * 8);
            oacc[hi][0] = __builtin_amdgcn_mfma_f32_16x16x32_bf16(P.s, vf0, oacc[hi][0], 0, 0, 0);
            oacc[hi][1] = __builtin_amdgcn_mfma_f32_16x16x32_bf16(P.s, vf1, oacc[hi][1], 0, 0, 0);
            rsacc[hi]   = __builtin_amdgcn_mfma_f32_16x16x32_bf16(P.s, ones, rsacc[hi], 0, 0, 0);
        }
        dmv = dmn;
#pragma unroll
        for (int hi = 0; hi < 2; ++hi) {
            kc[hi][0] = kn[hi][0];
            kc[hi][1] = kn[hi][1];
        }
    }

    // rowsums already reduced by the ones-MFMA (all u columns equal)
#pragma unroll
    for (int hi = 0; hi < 2; ++hi)
        if (u == 0) {
#pragma unroll
            for (int reg = 0; reg < 4; ++reg)
                rs_s[(w * 2 + hi) * 16 + 4 * g + reg] = rsacc[hi][reg];
        }
#pragma unroll
    for (int hi = 0; hi < 2; ++hi)
#pragma unroll
        for (int vt = 0; vt < 2; ++vt)
#pragma unroll
            for (int reg = 0; reg < 4; ++reg)
                comb[w * 1024 + (4 * g + reg) * 64 + hi * 32 + vt * 16 + u] =
                    (ushort)(__float_as_uint(oacc[hi][vt][reg]) >> 16);
    __syncthreads();

    // combine the 2 s-half waves per head pair; write full 256-col Y rows.
    // 512 threads: tl = t-row, f0 = 8-col group (f0 = hgp*64 + hi*32 + vt*16 + u).
    {
        const int tl = tid >> 5;
        const int f0 = (tid & 31) * 8;
        const int hgp2 = f0 >> 6;
        const int hi = (f0 >> 5) & 1;
        const int w0 = hgp2 * 2, w1 = w0 + 1;
        float rstot = rs_s[(w0 * 2 + hi) * 16 + tl] + rs_s[(w1 * 2 + hi) * 16 + tl];
        float inv = 1.f / (rstot + 1e-5f);
        uint4 pv0 = *(const uint4*)&comb[w0 * 1024 + tl * 64 + (f0 & 63)];
        uint4 pv1 = *(const uint4*)&comb[w1 * 1024 + tl * 64 + (f0 & 63)];
        float o[8];
        o[0] = upk(pv0.x) + upk(pv1.x);  o[1] = upkh(pv0.x) + upkh(pv1.x);
        o[2] = upk(pv0.y) + upk(pv1.y);  o[3] = upkh(pv0.y) + upkh(pv1.y);
        o[4] = upk(pv0.z) + upk(pv1.z);  o[5] = upkh(pv0.z) + upkh(pv1.z);
        o[6] = upk(pv0.w) + upk(pv1.w);  o[7] = upkh(pv0.w) + upkh(pv1.w);
        uint4 pwv;
        pwv.x = pk2(o[0] * inv, o[1] * inv); pwv.y = pk2(o[2] * inv, o[3] * inv);
        pwv.z = pk2(o[4] * inv, o[5] * inv); pwv.w = pk2(o[6] * inv, o[7] * inv);
        *(uint4*)(Yb + ((size_t)b * Tc + t0 + tl) * Dc + f0) = pwv;
    }
}

// ---------------- K3: fused Wo-GEMM+LN1 -> FFN-GEMM+LN2 (bf16 weights) ------
// grid 256, block 512 = 8 waves; block owns 16 rows x all 256 cols.
// ZZ tile lives in XOR-swizzled LDS between the two GEMMs; fp32 residual in regs.
__global__ __launch_bounds__(512) void out_fused(
    const ushort* __restrict__ Yb, const ushort* __restrict__ Woc,
    const float* __restrict__ bo, const float* __restrict__ x,
    const float* __restrict__ g1, const float* __restrict__ be1,
    const ushort* __restrict__ Wfc, const float* __restrict__ bfb,
    const float* __restrict__ g2, const float* __restrict__ be2,
    float* __restrict__ out)
{
    const int tid = threadIdx.x;
    const int w = tid >> 6;                 // wave 0..7: cols [w*32, w*32+32)
    const int l = tid & 63;
    const int u = l & 15, g = l >> 4;
    const int rbase = blockIdx.x * 16;

    __shared__ float red1[128], red2[128];
    __shared__ __align__(16) ushort ZZs[16 * 256];   // 8 KB, XOR-swizzled

    // ---- phase 1: Y @ Wo^T + bo + x, LN1 -> ZZ ----
    f32x4 acc[2];
    acc[0] = (f32x4){0.f, 0.f, 0.f, 0.f};
    acc[1] = (f32x4){0.f, 0.f, 0.f, 0.f};
    const ushort* arow = Yb + (size_t)(rbase + u) * 256 + g * 8;
#pragma unroll 2
    for (int k0 = 0; k0 < 256; k0 += 32) {
        short8 af = *(const short8*)(arow + k0);
#pragma unroll
        for (int nt = 0; nt < 2; ++nt) {
            short8 bfr = *(const short8*)(Woc + (size_t)(w * 32 + nt * 16 + u) * 256 + k0 + g * 8);
            acc[nt] = __builtin_amdgcn_mfma_f32_16x16x32_bf16(af, bfr, acc[nt], 0, 0, 0);
        }
    }

    float bv[2];
#pragma unroll
    for (int nt = 0; nt < 2; ++nt) bv[nt] = bo[w * 32 + nt * 16 + u];

    float sv[4][2];
#pragma unroll
    for (int reg = 0; reg < 4; ++reg) {
        const int row = rbase + 4 * g + reg;
        float s1 = 0.f, s2 = 0.f;
#pragma unroll
        for (int nt = 0; nt < 2; ++nt) {
            const int col = w * 32 + nt * 16 + u;
            float s = acc[nt][reg] + bv[nt] + x[(size_t)row * 256 + col];
            sv[reg][nt] = s;
            s1 += s;
            s2 = fmaf(s, s, s2);
        }
        s1 += __shfl_xor(s1, 1, 64); s2 += __shfl_xor(s2, 1, 64);
        s1 += __shfl_xor(s1, 2, 64); s2 += __shfl_xor(s2, 2, 64);
        s1 += __shfl_xor(s1, 4, 64); s2 += __shfl_xor(s2, 4, 64);
        s1 += __shfl_xor(s1, 8, 64); s2 += __shfl_xor(s2, 8, 64);
        if (u == 0) { red1[w * 16 + 4 * g + reg] = s1; red2[w * 16 + 4 * g + reg] = s2; }
    }
    __syncthreads();

    float zzv[4][2];   // fp32 residual for phase 2
#pragma unroll
    for (int reg = 0; reg < 4; ++reg) {
        const int rl = 4 * g + reg;
        float S1 = 0.f, S2 = 0.f;
#pragma unroll
        for (int ww = 0; ww < 8; ++ww) { S1 += red1[ww * 16 + rl]; S2 += red2[ww * 16 + rl]; }
        float mu = S1 * (1.f / 256.f);
        float var = S2 * (1.f / 256.f) - mu * mu;
        float rsig = rsqrtf(var + 1e-5f);
#pragma unroll
        for (int nt = 0; nt < 2; ++nt) {
            const int col = w * 32 + nt * 16 + u;
            float zz = (sv[reg][nt] - mu) * rsig * g1[col] + be1[col];
            zzv[reg][nt] = zz;
            const int boff = (rl * 512 + col * 2) ^ ((rl & 7) << 4);
            *(ushort*)((char*)ZZs + boff) = (ushort)bf16u(zz);
        }
    }
    __syncthreads();   // ZZ staged

    // ---- phase 2: ZZ @ Wf^T + bf, lrelu, + ZZ, LN2 -> out ----
    f32x4 acc2[2];
    acc2[0] = (f32x4){0.f, 0.f, 0.f, 0.f};
    acc2[1] = (f32x4){0.f, 0.f, 0.f, 0.f};
#pragma unroll 2
    for (int k0 = 0; k0 < 256; k0 += 32) {
        const int aoff = (u * 512 + (k0 + g * 8) * 2) ^ ((u & 7) << 4);
        short8 af = *(const short8*)((const char*)ZZs + aoff);
#pragma unroll
        for (int nt = 0; nt < 2; ++nt) {
            short8 bfr = *(const short8*)(Wfc + (size_t)(w * 32 + nt * 16 + u) * 256 + k0 + g * 8);
            acc2[nt] = __builtin_amdgcn_mfma_f32_16x16x32_bf16(af, bfr, acc2[nt], 0, 0, 0);
        }
    }

    float bv2[2];
#pragma unroll
    for (int nt = 0; nt < 2; ++nt) bv2[nt] = bfb[w * 32 + nt * 16 + u];

    float sv2[4][2];
#pragma unroll
    for (int reg = 0; reg < 4; ++reg) {
        float s1 = 0.f, s2 = 0.f;
#pragma unroll
        for (int nt = 0; nt < 2; ++nt) {
            float v = acc2[nt][reg] + bv2[nt];
            v = v >= 0.f ? v : 0.01f * v;
            float s = v + zzv[reg][nt];
            sv2[reg][nt] = s;
            s1 += s;
            s2 = fmaf(s, s, s2);
        }
        s1 += __shfl_xor(s1, 1, 64); s2 += __shfl_xor(s2, 1, 64);
        s1 += __shfl_xor(s1, 2, 64); s2 += __shfl_xor(s2, 2, 64);
        s1 += __shfl_xor(s1, 4, 64); s2 += __shfl_xor(s2, 4, 64);
        s1 += __shfl_xor(s1, 8, 64); s2 += __shfl_xor(s2, 8, 64);
        if (u == 0) { red1[w * 16 + 4 * g + reg] = s1; red2[w * 16 + 4 * g + reg] = s2; }
    }
    __syncthreads();

#pragma unroll
    for (int reg = 0; reg < 4; ++reg) {
        const int row = rbase + 4 * g + reg;
        const int rl = 4 * g + reg;
        float S1 = 0.f, S2 = 0.f;
#pragma unroll
        for (int ww = 0; ww < 8; ++ww) { S1 += red1[ww * 16 + rl]; S2 += red2[ww * 16 + rl]; }
        float mu = S1 * (1.f / 256.f);
        float var = S2 * (1.f / 256.f) - mu * mu;
        float rsig = rsqrtf(var + 1e-5f);
#pragma unroll
        for (int nt = 0; nt < 2; ++nt) {
            const int col = w * 32 + nt * 16 + u;
            out[(size_t)row * 256 + col] = (sv2[reg][nt] - mu) * rsig * g2[col] + be2[col];
        }
    }
}

extern "C" void kernel_launch(void* const* d_in, const int* in_sizes, int n_in,
                              void* d_out, int out_size, void* d_ws, size_t ws_size,
                              hipStream_t stream) {
    const float* x    = (const float*)d_in[0];
    const int*   mask = (const int*)d_in[1];
    const float* rel  = (const float*)d_in[2];
    const float* Wq   = (const float*)d_in[3];
    const float* Wk   = (const float*)d_in[4];
    const float* Wv   = (const float*)d_in[5];
    const float* pw1  = (const float*)d_in[6];
    const float* pb1  = (const float*)d_in[7];
    const float* pw2  = (const float*)d_in[8];
    const float* pb2  = (const float*)d_in[9];
    const float* Wo   = (const float*)d_in[10];
    const float* bo   = (const float*)d_in[11];
    const float* Wf   = (const float*)d_in[12];
    const float* bf   = (const float*)d_in[13];
    const float* g1   = (const float*)d_in[14];
    const float* be1  = (const float*)d_in[15];
    const float* g2   = (const float*)d_in[16];
    const float* be2  = (const float*)d_in[17];
    float* out = (float*)d_out;

    char* wsb = (char*)d_ws;
    ushort* Qb    = (ushort*)(wsb);                                      // 2 MB
    ushort* Kb    = (ushort*)(wsb + (size_t)(2 << 20));                  // 2 MB
    ushort* Vt    = (ushort*)(wsb + (size_t)(4 << 20));                  // 2 MB (tile-major)
    ushort* Yb    = (ushort*)(wsb + (size_t)(6 << 20));                  // 2 MB
    ushort* Wqkvc = (ushort*)(wsb + (size_t)(8 << 20));                  // 384 KB
    ushort* Woc   = (ushort*)(wsb + (size_t)(8 << 20) + (512 << 10));    // 128 KB
    ushort* Wfc   = (ushort*)(wsb + (size_t)(8 << 20) + (768 << 10));    // 128 KB

    cast_w<<<320, 256, 0, stream>>>(Wq, Wk, Wv, Wo, Wf, Wqkvc, Woc, Wfc);
    qkv_direct<<<dim3(256, 3), 256, 0, stream>>>(x, Wqkvc, Qb, Kb, Vt);
    attn_fused<<<256, 512, 0, stream>>>(Qb, Kb, Vt, rel, mask,
                                        pw1, pb1, pw2, pb2, Yb);
    out_fused<<<256, 512, 0, stream>>>(Yb, Woc, bo, x, g1, be1,
                                       Wfc, bf, g2, be2, out);
}

// Round 11
// 170.056 us; speedup vs baseline: 1.0980x; 1.0064x over previous
//
#include <hip/hip_runtime.h>
#include <math.h>

#define Tc 1024
#define Dc 256
#define Hc 8
#define Cc 16
#define LUTN 256

typedef __attribute__((ext_vector_type(8))) short short8;
typedef __attribute__((ext_vector_type(4))) float f32x4;

__device__ __forceinline__ unsigned bf16u(float x) {   // RNE
    unsigned u = __float_as_uint(x);
    return (u + 0x7FFFu + ((u >> 16) & 1u)) >> 16;
}
__device__ __forceinline__ unsigned pk2(float lo, float hi) {
    return bf16u(lo) | (bf16u(hi) << 16);
}
__device__ __forceinline__ unsigned pk2t(float lo, float hi) {  // truncating, 1 inst
    return __builtin_amdgcn_perm(__float_as_uint(hi), __float_as_uint(lo), 0x07060302u);
}
__device__ __forceinline__ float upk(unsigned v) { return __uint_as_float(v << 16); }
__device__ __forceinline__ float upkh(unsigned v) { return __uint_as_float(v & 0xffff0000u); }

__device__ __forceinline__ short8 packW8(const float* __restrict__ p) {
    float4 b0 = *(const float4*)(p);
    float4 b1 = *(const float4*)(p + 4);
    union { short8 s; unsigned wds[4]; } B;
    B.wds[0] = pk2(b0.x, b0.y); B.wds[1] = pk2(b0.z, b0.w);
    B.wds[2] = pk2(b1.x, b1.y); B.wds[3] = pk2(b1.z, b1.w);
    return B.s;
}

// ---------------- K0: cast the 5 weight matrices to bf16 --------------------
// grid 320, block 256; 4 elems/thread.
__global__ __launch_bounds__(256) void cast_w(
    const float* __restrict__ Wq, const float* __restrict__ Wk,
    const float* __restrict__ Wv, const float* __restrict__ Wo,
    const float* __restrict__ Wf,
    ushort* __restrict__ Wqkvc, ushort* __restrict__ Woc,
    ushort* __restrict__ Wfc)
{
    const int e = blockIdx.x * 1024 + threadIdx.x * 4;
    const float* src; ushort* dst; int off;
    if      (e <  65536) { src = Wq; dst = Wqkvc;          off = e; }
    else if (e < 131072) { src = Wk; dst = Wqkvc + 65536;  off = e - 65536; }
    else if (e < 196608) { src = Wv; dst = Wqkvc + 131072; off = e - 131072; }
    else if (e < 262144) { src = Wo; dst = Woc;            off = e - 196608; }
    else                 { src = Wf; dst = Wfc;            off = e - 262144; }
    float4 v = *(const float4*)(src + off);
    uint2 p; p.x = pk2(v.x, v.y); p.y = pk2(v.z, v.w);
    *(uint2*)(dst + off) = p;
}

// ---------------- K1: QKV direct-MFMA GEMM (no LDS, no barriers) ------------
// grid (256, 3), block 256 = 4 waves. Wave: C tile 16 rows x 64 cols.
// A (x) read fp32 and RNE-packed in-register; B from precast bf16 weights.
__global__ __launch_bounds__(256) void qkv_direct(
    const float* __restrict__ x, const ushort* __restrict__ Wqkv,
    ushort* __restrict__ Qb, ushort* __restrict__ Kb, ushort* __restrict__ Vt)
{
    const int tid = threadIdx.x;
    const int w = tid >> 6;
    const int l = tid & 63;
    const int u = l & 15, g = l >> 4;
    const int rbase = blockIdx.x * 16;
    const int cb = (blockIdx.y * 4 + w) * 64;     // 0..704

    f32x4 acc[4];
#pragma unroll
    for (int nt = 0; nt < 4; ++nt) acc[nt] = (f32x4){0.f, 0.f, 0.f, 0.f};

    const float* arow = x + (size_t)(rbase + u) * 256 + g * 8;
#pragma unroll 2
    for (int k0 = 0; k0 < 256; k0 += 32) {
        short8 af = packW8(arow + k0);
#pragma unroll
        for (int nt = 0; nt < 4; ++nt) {
            short8 bfr = *(const short8*)(Wqkv + (size_t)(cb + nt * 16 + u) * 256 + k0 + g * 8);
            acc[nt] = __builtin_amdgcn_mfma_f32_16x16x32_bf16(af, bfr, acc[nt], 0, 0, 0);
        }
    }

    const int mat = cb >> 8;
    const int fcb = cb & 255;
    if (mat < 2) {
        ushort* Out = (mat == 0) ? Qb : Kb;
#pragma unroll
        for (int hp = 0; hp < 2; ++hp) {          // two heads per wave tile
            const int head = (fcb >> 5) + hp;
#pragma unroll
            for (int reg = 0; reg < 4; ++reg) {
                float ss = acc[2 * hp][reg] * acc[2 * hp][reg]
                         + acc[2 * hp + 1][reg] * acc[2 * hp + 1][reg];
                ss += __shfl_xor(ss, 1, 64);
                ss += __shfl_xor(ss, 2, 64);
                ss += __shfl_xor(ss, 4, 64);
                ss += __shfl_xor(ss, 8, 64);
                float scn = 1.f / fmaxf(sqrtf(ss), 1e-12f);
                const int t = rbase + 4 * g + reg;
                const int bb = t >> 10, tt = t & 1023;
                const size_t base = ((size_t)(bb * 8 + head) * Tc + tt) * 32;
                Out[base + u]      = (ushort)bf16u(acc[2 * hp][reg] * scn);
                Out[base + 16 + u] = (ushort)bf16u(acc[2 * hp + 1][reg] * scn);
            }
        }
    } else {
#pragma unroll
        for (int nt = 0; nt < 4; ++nt) {
            const int head = (fcb >> 5) + (nt >> 1);
            const int vt = nt & 1;
#pragma unroll
            for (int reg = 0; reg < 4; ++reg) {
                const int s = rbase + 4 * g + reg;
                const int bb = s >> 10, ss = s & 1023;
                const int bh = bb * 8 + head;
                Vt[(((size_t)bh * 32 + (ss >> 5)) * 2 + vt) * 512 + u * 32 + (ss & 31)] =
                    (ushort)bf16u(acc[nt][reg]);
            }
        }
    }
}

// ---------------- K2: fused flash attention, all 8 heads per block ----------
// grid 256 = (t-tile, b), block 1024 = 16 waves: wave w -> head pair (w>>2),
// s-quarter (w&3)*256, 8 iters/wave. ONLY change vs R9: wave decomposition
// 8x512s -> 16x256s (2->4 waves/SIMD) to cover the latency chain the R9
// counters exposed (Occ 20%, MFMA 4%, VALU 28%, HBM 6%).
__global__ __launch_bounds__(1024) void attn_fused(
    const ushort* __restrict__ Qb, const ushort* __restrict__ Kb,
    const ushort* __restrict__ Vt,
    const float* __restrict__ rel, const int* __restrict__ msk,
    const float* __restrict__ pw1, const float* __restrict__ pb1,
    const float* __restrict__ pw2, const float* __restrict__ pb2,
    ushort* __restrict__ Yb)
{
    const int tid = threadIdx.x;
    const int w = tid >> 6;
    const int l = tid & 63;
    const int u = l & 15;
    const int g = l >> 4;
    const int bid = blockIdx.x;
    const int b   = (bid >> 1) & 3;
    const int tt  = (bid >> 3) * 2 + (bid & 1);   // 0..63
    const int t0  = tt * 16;

    __shared__ __align__(16) ushort dm_s[16 * 1024];     // 32 KB, XOR-swizzled
    __shared__ __align__(16) ushort lut_s[256 * 16];     // 8 KB [bin][head]{a,b}
    __shared__ __align__(16) ushort comb[16 * 16 * 64];  // 32 KB bf16 partials
    __shared__ float rs_s[16 * 2 * 16];                  // 2 KB [w][hi][t]

    // ---- build the 8-head PWL LUT (each (bin, head-pair) by one thread) ----
    {
        const int bin = tid & 255;
        const int hb  = (tid >> 8) * 2;
        const float d0 = bin * (1.f / LUTN), d1 = (bin + 1) * (1.f / LUTN);
#pragma unroll
        for (int hp = 0; hp < 2; ++hp) {
            const int h = hb + hp;
            float y0 = pb2[h], y1 = pb2[h];
#pragma unroll
            for (int cc = 0; cc < Cc; ++cc) {
                float w1 = pw1[h * Cc + cc], b1 = pb1[h * Cc + cc], w2 = pw2[h * Cc + cc];
                float h0 = fmaf(w1, d0, b1), h1 = fmaf(w1, d1, b1);
                y0 = fmaf(w2, h0 >= 0.f ? h0 : 0.01f * h0, y0);
                y1 = fmaf(w2, h1 >= 0.f ? h1 : 0.01f * h1, y1);
            }
            float a = (y1 - y0) * (float)LUTN;
            float bq = y0 - a * d0;
            lut_s[bin * 16 + h * 2]     = (ushort)bf16u(a);
            lut_s[bin * 16 + h * 2 + 1] = (ushort)bf16u(bq);
        }
    }

    // ---- stage rel+mask -> swizzled bf16 dm_s (read once chip-wide) --------
    {
        const int row = tid >> 6;            // 0..15
        const int lc  = tid & 63;
        const float* rrow = rel + ((size_t)b * Tc + t0 + row) * Tc;
        const int*   mrow = msk + ((size_t)b * Tc + t0 + row) * Tc;
        const int swz = (row & 7) << 4;
#pragma unroll
        for (int i = 0; i < 2; ++i) {
            const int s0 = lc * 8 + i * 512;
            float4 d0v = *(const float4*)(rrow + s0);
            float4 d1v = *(const float4*)(rrow + s0 + 4);
            int4   m0v = *(const int4*)(mrow + s0);
            int4   m1v = *(const int4*)(mrow + s0 + 4);
            uint4 p;
            p.x = (m0v.x ? 0xBF80u : bf16u(d0v.x)) | ((m0v.y ? 0xBF80u : bf16u(d0v.y)) << 16);
            p.y = (m0v.z ? 0xBF80u : bf16u(d0v.z)) | ((m0v.w ? 0xBF80u : bf16u(d0v.w)) << 16);
            p.z = (m1v.x ? 0xBF80u : bf16u(d1v.x)) | ((m1v.y ? 0xBF80u : bf16u(d1v.y)) << 16);
            p.w = (m1v.z ? 0xBF80u : bf16u(d1v.z)) | ((m1v.w ? 0xBF80u : bf16u(d1v.w)) << 16);
            *(uint4*)((char*)dm_s + ((row * 2048 + s0 * 2) ^ swz)) = p;
        }
    }

    const int hgp = w >> 2;                     // head pair 0..3
    const int bh0 = b * 8 + hgp * 2;
    short8 qf[2];
#pragma unroll
    for (int hi = 0; hi < 2; ++hi)
        qf[hi] = *(const short8*)(Qb + (((size_t)(bh0 + hi) * Tc + t0 + u) * 32 + g * 8));

    const short8 ones = (short8){0x3F80, 0x3F80, 0x3F80, 0x3F80,
                                 0x3F80, 0x3F80, 0x3F80, 0x3F80};

    f32x4 oacc[2][2];
    f32x4 rsacc[2];
#pragma unroll
    for (int hi = 0; hi < 2; ++hi) {
        oacc[hi][0] = (f32x4){0.f, 0.f, 0.f, 0.f};
        oacc[hi][1] = (f32x4){0.f, 0.f, 0.f, 0.f};
        rsacc[hi]   = (f32x4){0.f, 0.f, 0.f, 0.f};
    }

    __syncthreads();   // lut + dm staged

    const int s_begin = (w & 3) * 256;
    const int dswz = (u & 7) << 4;

    // software-rotated K + dm (one iteration ahead; no barriers in the loop)
    short8 kc[2][2];
#pragma unroll
    for (int hi = 0; hi < 2; ++hi) {
        const size_t kb = ((size_t)(bh0 + hi) * Tc + s_begin + 2 * u) * 32 + g * 8;
        kc[hi][0] = *(const short8*)(Kb + kb);
        kc[hi][1] = *(const short8*)(Kb + kb + 32);
    }
    uint4 dmv = *(const uint4*)((const char*)dm_s + ((u * 2048 + (s_begin + 8 * g) * 2) ^ dswz));

    for (int sc = s_begin; sc < s_begin + 256; sc += 32) {
        const int nx = (sc + 32 < s_begin + 256) ? sc + 32 : s_begin;  // clamped prefetch
        uint4 dmn = *(const uint4*)((const char*)dm_s + ((u * 2048 + (nx + 8 * g) * 2) ^ dswz));
        short8 kn[2][2];
#pragma unroll
        for (int hi = 0; hi < 2; ++hi) {
            const size_t kb = ((size_t)(bh0 + hi) * Tc + nx + 2 * u) * 32 + g * 8;
            kn[hi][0] = *(const short8*)(Kb + kb);
            kn[hi][1] = *(const short8*)(Kb + kb + 32);
        }

        // d for s = sc + 8g + {2j, 2j+1}, row t = u (LDS, swizzled, prefetched)
        const unsigned dw[4] = {dmv.x, dmv.y, dmv.z, dmv.w};
        float dA[4], dB[4];
#pragma unroll
        for (int j = 0; j < 4; ++j) {
            dA[j] = upk(dw[j]);
            dB[j] = upkh(dw[j]);
        }
        float biasA[4][2], biasB[4][2];
#pragma unroll
        for (int j = 0; j < 4; ++j) {
            int iA = (int)(dA[j] * (float)LUTN);
            int iB = (int)(dB[j] * (float)LUTN);
            iA = iA < 0 ? 0 : (iA > LUTN - 1 ? LUTN - 1 : iA);
            iB = iB < 0 ? 0 : (iB > LUTN - 1 ? LUTN - 1 : iB);
            uint2 wA = *(const uint2*)(lut_s + iA * 16 + hgp * 4);
            uint2 wB = *(const uint2*)(lut_s + iB * 16 + hgp * 4);
            biasA[j][0] = fmaf(upk(wA.x), dA[j], upkh(wA.x));
            biasA[j][1] = fmaf(upk(wA.y), dA[j], upkh(wA.y));
            biasB[j][0] = fmaf(upk(wB.x), dB[j], upkh(wB.x));
            biasB[j][1] = fmaf(upk(wB.y), dB[j], upkh(wB.y));
        }
#pragma unroll
        for (int hi = 0; hi < 2; ++hi) {
            const f32x4 z4 = (f32x4){0.f, 0.f, 0.f, 0.f};
            // swapped operands: rows of C = K rows (s), cols = Q rows (t=u)
            f32x4 sA = __builtin_amdgcn_mfma_f32_16x16x32_bf16(kc[hi][0], qf[hi], z4, 0, 0, 0);
            f32x4 sB = __builtin_amdgcn_mfma_f32_16x16x32_bf16(kc[hi][1], qf[hi], z4, 0, 0, 0);
            union { short8 s; unsigned w4[4]; } P;
#pragma unroll
            for (int j = 0; j < 4; ++j) {
                float zA = (dA[j] < 0.f) ? 0.f : __expf(sA[j] - biasA[j][hi]);
                float zB = (dB[j] < 0.f) ? 0.f : __expf(sB[j] - biasB[j][hi]);
                P.w4[j] = pk2t(zA, zB);
            }
            const ushort* vb = Vt + ((size_t)(bh0 + hi) * 32 + (sc >> 5)) * 1024;
            short8 vf0 = *(const short8*)(vb + u * 32 + g * 8);
            short8 vf1 = *(const short8*)(vb + 512 + u * 32 + g * 8);
            oacc[hi][0] = __builtin_amdgcn_mfma_f32_16x16x32_bf16(P.s, vf0, oacc[hi][0], 0, 0, 0);
            oacc[hi][1] = __builtin_amdgcn_mfma_f32_16x16x32_bf16(P.s, vf1, oacc[hi][1], 0, 0, 0);
            rsacc[hi]   = __builtin_amdgcn_mfma_f32_16x16x32_bf16(P.s, ones, rsacc[hi], 0, 0, 0);
        }
        dmv = dmn;
#pragma unroll
        for (int hi = 0; hi < 2; ++hi) {
            kc[hi][0] = kn[hi][0];
            kc[hi][1] = kn[hi][1];
        }
    }

    // rowsums already reduced by the ones-MFMA (all u columns equal)
#pragma unroll
    for (int hi = 0; hi < 2; ++hi)
        if (u == 0) {
#pragma unroll
            for (int reg = 0; reg < 4; ++reg)
                rs_s[(w * 2 + hi) * 16 + 4 * g + reg] = rsacc[hi][reg];
        }
#pragma unroll
    for (int hi = 0; hi < 2; ++hi)
#pragma unroll
        for (int vt = 0; vt < 2; ++vt)
#pragma unroll
            for (int reg = 0; reg < 4; ++reg)
                comb[w * 1024 + (4 * g + reg) * 64 + hi * 32 + vt * 16 + u] =
                    (ushort)(__float_as_uint(oacc[hi][vt][reg]) >> 16);
    __syncthreads();

    // combine the 4 s-quarter waves per head pair; write full 256-col Y rows.
    if (tid < 512) {
        const int tl = tid >> 5;
        const int f0 = (tid & 31) * 8;
        const int hgp2 = f0 >> 6;
        const int hi = (f0 >> 5) & 1;
        const int w0 = hgp2 * 4;
        float rstot = rs_s[((w0 + 0) * 2 + hi) * 16 + tl]
                    + rs_s[((w0 + 1) * 2 + hi) * 16 + tl]
                    + rs_s[((w0 + 2) * 2 + hi) * 16 + tl]
                    + rs_s[((w0 + 3) * 2 + hi) * 16 + tl];
        float inv = 1.f / (rstot + 1e-5f);
        float o[8];
#pragma unroll
        for (int k = 0; k < 8; ++k) o[k] = 0.f;
#pragma unroll
        for (int q = 0; q < 4; ++q) {
            uint4 pv = *(const uint4*)&comb[(w0 + q) * 1024 + tl * 64 + (f0 & 63)];
            o[0] += upk(pv.x); o[1] += upkh(pv.x);
            o[2] += upk(pv.y); o[3] += upkh(pv.y);
            o[4] += upk(pv.z); o[5] += upkh(pv.z);
            o[6] += upk(pv.w); o[7] += upkh(pv.w);
        }
        uint4 pwv;
        pwv.x = pk2(o[0] * inv, o[1] * inv); pwv.y = pk2(o[2] * inv, o[3] * inv);
        pwv.z = pk2(o[4] * inv, o[5] * inv); pwv.w = pk2(o[6] * inv, o[7] * inv);
        *(uint4*)(Yb + ((size_t)b * Tc + t0 + tl) * Dc + f0) = pwv;
    }
}

// ---------------- K3: fused Wo-GEMM+LN1 -> FFN-GEMM+LN2 (bf16 weights) ------
// grid 256, block 512 = 8 waves; block owns 16 rows x all 256 cols.
// ZZ tile lives in XOR-swizzled LDS between the two GEMMs; fp32 residual in regs.
__global__ __launch_bounds__(512) void out_fused(
    const ushort* __restrict__ Yb, const ushort* __restrict__ Woc,
    const float* __restrict__ bo, const float* __restrict__ x,
    const float* __restrict__ g1, const float* __restrict__ be1,
    const ushort* __restrict__ Wfc, const float* __restrict__ bfb,
    const float* __restrict__ g2, const float* __restrict__ be2,
    float* __restrict__ out)
{
    const int tid = threadIdx.x;
    const int w = tid >> 6;                 // wave 0..7: cols [w*32, w*32+32)
    const int l = tid & 63;
    const int u = l & 15, g = l >> 4;
    const int rbase = blockIdx.x * 16;

    __shared__ float red1[128], red2[128];
    __shared__ __align__(16) ushort ZZs[16 * 256];   // 8 KB, XOR-swizzled

    // ---- phase 1: Y @ Wo^T + bo + x, LN1 -> ZZ ----
    f32x4 acc[2];
    acc[0] = (f32x4){0.f, 0.f, 0.f, 0.f};
    acc[1] = (f32x4){0.f, 0.f, 0.f, 0.f};
    const ushort* arow = Yb + (size_t)(rbase + u) * 256 + g * 8;
#pragma unroll 2
    for (int k0 = 0; k0 < 256; k0 += 32) {
        short8 af = *(const short8*)(arow + k0);
#pragma unroll
        for (int nt = 0; nt < 2; ++nt) {
            short8 bfr = *(const short8*)(Woc + (size_t)(w * 32 + nt * 16 + u) * 256 + k0 + g * 8);
            acc[nt] = __builtin_amdgcn_mfma_f32_16x16x32_bf16(af, bfr, acc[nt], 0, 0, 0);
        }
    }

    float bv[2];
#pragma unroll
    for (int nt = 0; nt < 2; ++nt) bv[nt] = bo[w * 32 + nt * 16 + u];

    float sv[4][2];
#pragma unroll
    for (int reg = 0; reg < 4; ++reg) {
        const int row = rbase + 4 * g + reg;
        float s1 = 0.f, s2 = 0.f;
#pragma unroll
        for (int nt = 0; nt < 2; ++nt) {
            const int col = w * 32 + nt * 16 + u;
            float s = acc[nt][reg] + bv[nt] + x[(size_t)row * 256 + col];
            sv[reg][nt] = s;
            s1 += s;
            s2 = fmaf(s, s, s2);
        }
        s1 += __shfl_xor(s1, 1, 64); s2 += __shfl_xor(s2, 1, 64);
        s1 += __shfl_xor(s1, 2, 64); s2 += __shfl_xor(s2, 2, 64);
        s1 += __shfl_xor(s1, 4, 64); s2 += __shfl_xor(s2, 4, 64);
        s1 += __shfl_xor(s1, 8, 64); s2 += __shfl_xor(s2, 8, 64);
        if (u == 0) { red1[w * 16 + 4 * g + reg] = s1; red2[w * 16 + 4 * g + reg] = s2; }
    }
    __syncthreads();

    float zzv[4][2];   // fp32 residual for phase 2
#pragma unroll
    for (int reg = 0; reg < 4; ++reg) {
        const int rl = 4 * g + reg;
        float S1 = 0.f, S2 = 0.f;
#pragma unroll
        for (int ww = 0; ww < 8; ++ww) { S1 += red1[ww * 16 + rl]; S2 += red2[ww * 16 + rl]; }
        float mu = S1 * (1.f / 256.f);
        float var = S2 * (1.f / 256.f) - mu * mu;
        float rsig = rsqrtf(var + 1e-5f);
#pragma unroll
        for (int nt = 0; nt < 2; ++nt) {
            const int col = w * 32 + nt * 16 + u;
            float zz = (sv[reg][nt] - mu) * rsig * g1[col] + be1[col];
            zzv[reg][nt] = zz;
            const int boff = (rl * 512 + col * 2) ^ ((rl & 7) << 4);
            *(ushort*)((char*)ZZs + boff) = (ushort)bf16u(zz);
        }
    }
    __syncthreads();   // ZZ staged

    // ---- phase 2: ZZ @ Wf^T + bf, lrelu, + ZZ, LN2 -> out ----
    f32x4 acc2[2];
    acc2[0] = (f32x4){0.f, 0.f, 0.f, 0.f};
    acc2[1] = (f32x4){0.f, 0.f, 0.f, 0.f};
#pragma unroll 2
    for (int k0 = 0; k0 < 256; k0 += 32) {
        const int aoff = (u * 512 + (k0 + g * 8) * 2) ^ ((u & 7) << 4);
        short8 af = *(const short8*)((const char*)ZZs + aoff);
#pragma unroll
        for (int nt = 0; nt < 2; ++nt) {
            short8 bfr = *(const short8*)(Wfc + (size_t)(w * 32 + nt * 16 + u) * 256 + k0 + g * 8);
            acc2[nt] = __builtin_amdgcn_mfma_f32_16x16x32_bf16(af, bfr, acc2[nt], 0, 0, 0);
        }
    }

    float bv2[2];
#pragma unroll
    for (int nt = 0; nt < 2; ++nt) bv2[nt] = bfb[w * 32 + nt * 16 + u];

    float sv2[4][2];
#pragma unroll
    for (int reg = 0; reg < 4; ++reg) {
        float s1 = 0.f, s2 = 0.f;
#pragma unroll
        for (int nt = 0; nt < 2; ++nt) {
            float v = acc2[nt][reg] + bv2[nt];
            v = v >= 0.f ? v : 0.01f * v;
            float s = v + zzv[reg][nt];
            sv2[reg][nt] = s;
            s1 += s;
            s2 = fmaf(s, s, s2);
        }
        s1 += __shfl_xor(s1, 1, 64); s2 += __shfl_xor(s2, 1, 64);
        s1 += __shfl_xor(s1, 2, 64); s2 += __shfl_xor(s2, 2, 64);
        s1 += __shfl_xor(s1, 4, 64); s2 += __shfl_xor(s2, 4, 64);
        s1 += __shfl_xor(s1, 8, 64); s2 += __shfl_xor(s2, 8, 64);
        if (u == 0) { red1[w * 16 + 4 * g + reg] = s1; red2[w * 16 + 4 * g + reg] = s2; }
    }
    __syncthreads();

#pragma unroll
    for (int reg = 0; reg < 4; ++reg) {
        const int row = rbase + 4 * g + reg;
        const int rl = 4 * g + reg;
        float S1 = 0.f, S2 = 0.f;
#pragma unroll
        for (int ww = 0; ww < 8; ++ww) { S1 += red1[ww * 16 + rl]; S2 += red2[ww * 16 + rl]; }
        float mu = S1 * (1.f / 256.f);
        float var = S2 * (1.f / 256.f) - mu * mu;
        float rsig = rsqrtf(var + 1e-5f);
#pragma unroll
        for (int nt = 0; nt < 2; ++nt) {
            const int col = w * 32 + nt * 16 + u;
            out[(size_t)row * 256 + col] = (sv2[reg][nt] - mu) * rsig * g2[col] + be2[col];
        }
    }
}

extern "C" void kernel_launch(void* const* d_in, const int* in_sizes, int n_in,
                              void* d_out, int out_size, void* d_ws, size_t ws_size,
                              hipStream_t stream) {
    const float* x    = (const float*)d_in[0];
    const int*   mask = (const int*)d_in[1];
    const float* rel  = (const float*)d_in[2];
    const float* Wq   = (const float*)d_in[3];
    const float* Wk   = (const float*)d_in[4];
    const float* Wv   = (const float*)d_in[5];
    const float* pw1  = (const float*)d_in[6];
    const float* pb1  = (const float*)d_in[7];
    const float* pw2  = (const float*)d_in[8];
    const float* pb2  = (const float*)d_in[9];
    const float* Wo   = (const float*)d_in[10];
    const float* bo   = (const float*)d_in[11];
    const float* Wf   = (const float*)d_in[12];
    const float* bf   = (const float*)d_in[13];
    const float* g1   = (const float*)d_in[14];
    const float* be1  = (const float*)d_in[15];
    const float* g2   = (const float*)d_in[16];
    const float* be2  = (const float*)d_in[17];
    float* out = (float*)d_out;

    char* wsb = (char*)d_ws;
    ushort* Qb    = (ushort*)(wsb);                                      // 2 MB
    ushort* Kb    = (ushort*)(wsb + (size_t)(2 << 20));                  // 2 MB
    ushort* Vt    = (ushort*)(wsb + (size_t)(4 << 20));                  // 2 MB (tile-major)
    ushort* Yb    = (ushort*)(wsb + (size_t)(6 << 20));                  // 2 MB
    ushort* Wqkvc = (ushort*)(wsb + (size_t)(8 << 20));                  // 384 KB
    ushort* Woc   = (ushort*)(wsb + (size_t)(8 << 20) + (512 << 10));    // 128 KB
    ushort* Wfc   = (ushort*)(wsb + (size_t)(8 << 20) + (768 << 10));    // 128 KB

    cast_w<<<320, 256, 0, stream>>>(Wq, Wk, Wv, Wo, Wf, Wqkvc, Woc, Wfc);
    qkv_direct<<<dim3(256, 3), 256, 0, stream>>>(x, Wqkvc, Qb, Kb, Vt);
    attn_fused<<<256, 1024, 0, stream>>>(Qb, Kb, Vt, rel, mask,
                                         pw1, pb1, pw2, pb2, Yb);
    out_fused<<<256, 512, 0, stream>>>(Yb, Woc, bo, x, g1, be1,
                                       Wfc, bf, g2, be2, out);
}